// Round 6
// baseline (473.627 us; speedup 1.0000x reference)
//
#include <hip/hip_runtime.h>
#include <hip/hip_bf16.h>

#define E_EDGES 1000000
#define N_NODES 100000
#define HDIM 128
#define BM 64
#define LDP 136   // padded LDS row stride for bf16 tiles
#define NB 1024   // src buckets (src>>7 -> 0..781)

typedef __attribute__((ext_vector_type(8))) short short8;
typedef __attribute__((ext_vector_type(4))) float f32x4;

static __device__ __forceinline__ short f2bf(float f) {
  unsigned int u = __float_as_uint(f);
  unsigned int r = (u + 0x7FFFu + ((u >> 16) & 1u)) >> 16;
  return (short)r;
}
static __device__ __forceinline__ float bf2f(short s) {
  return __uint_as_float(((unsigned int)(unsigned short)s) << 16);
}
static __device__ __forceinline__ unsigned int pack_bf16_rn(float lo, float hi) {
  __hip_bfloat162 h = __float22bfloat162_rn(make_float2(lo, hi));
  unsigned int u;
  __builtin_memcpy(&u, &h, 4);
  return u;
}

// ---- k0: transpose + bf16-ize weights: Wt[out][in] row-major ----
__global__ void prep_weights(const float* __restrict__ Wp, const float* __restrict__ Wc,
                             const float* __restrict__ W1, const float* __restrict__ W2,
                             short* __restrict__ wp_t, short* __restrict__ wc_t,
                             short* __restrict__ w1_t, float* __restrict__ w2v) {
  int i = blockIdx.x * 256 + threadIdx.x;
  if (i < HDIM * HDIM) {
    int o = i >> 7, k = i & (HDIM - 1);
    wp_t[i] = f2bf(Wp[k * HDIM + o]);
    wc_t[i] = f2bf(Wc[k * HDIM + o]);
  }
  if (i < HDIM * 3 * HDIM) {
    int o = i / (3 * HDIM), k = i - o * (3 * HDIM);
    w1_t[i] = f2bf(W1[k * HDIM + o]);
  }
  if (i < HDIM) w2v[i] = W2[i];
}

// ---- counting sort of edges by src>>7 ----
__global__ __launch_bounds__(512) void hist_kernel(const int* __restrict__ ei,
                                                   int* __restrict__ hist) {
  __shared__ int h[NB];
  const int t = threadIdx.x;
  h[t] = 0; h[t + 512] = 0;
  __syncthreads();
  const int base = blockIdx.x * 2048;
#pragma unroll
  for (int i = 0; i < 4; ++i) {
    int e = base + i * 512 + t;
    if (e < E_EDGES) atomicAdd(&h[ei[e] >> 7], 1);
  }
  __syncthreads();
  if (h[t]) atomicAdd(&hist[t], h[t]);
  if (h[t + 512]) atomicAdd(&hist[t + 512], h[t + 512]);
}

__global__ __launch_bounds__(NB) void scan_kernel(const int* __restrict__ hist,
                                                  int* __restrict__ cursor) {
  __shared__ int s[NB];
  const int t = threadIdx.x;
  const int my = hist[t];
  s[t] = my;
  __syncthreads();
  for (int off = 1; off < NB; off <<= 1) {
    int v = (t >= off) ? s[t - off] : 0;
    __syncthreads();
    s[t] += v;
    __syncthreads();
  }
  cursor[t] = s[t] - my;  // exclusive prefix
}

__global__ __launch_bounds__(512) void scatter_kernel(const int* __restrict__ ei,
                                                      int* __restrict__ cursor,
                                                      int* __restrict__ perm) {
  int e = blockIdx.x * 512 + threadIdx.x;
  if (e < E_EDGES) {
    int b = ei[e] >> 7;
    int pos = atomicAdd(&cursor[b], 1);
    perm[pos] = e;
  }
}

// ---- k1: per-node precompute ----
__global__ __launch_bounds__(256) void node_precompute(
    const float* __restrict__ x, const float* __restrict__ b_p,
    const float* __restrict__ b_c, const float* __restrict__ b1,
    const short* __restrict__ wp_t, const short* __restrict__ wc_t,
    const short* __restrict__ w1_t,
    short* __restrict__ x_bf, short* __restrict__ Abuf, short* __restrict__ Bbuf) {
  __shared__ __align__(16) short Xt[BM * LDP];
  __shared__ __align__(16) short Yp[BM * LDP];
  __shared__ __align__(16) short Yc[BM * LDP];

  const int t = threadIdx.x;
  const int n0 = blockIdx.x * BM;

  {
    const int lane16 = t & 15, rq = t >> 4, c0 = lane16 * 8;
#pragma unroll
    for (int pass = 0; pass < 4; ++pass) {
      const int row = pass * 16 + rq;
      const int n = n0 + row;
      short8 v;
      if (n < N_NODES) {
        const float* ps = x + (size_t)n * HDIM + c0;
        float4 a = *(const float4*)ps;
        float4 b = *(const float4*)(ps + 4);
        float f[8] = {a.x, a.y, a.z, a.w, b.x, b.y, b.z, b.w};
#pragma unroll
        for (int j = 0; j < 8; ++j) v[j] = f2bf(f[j]);
        *(short8*)&x_bf[(size_t)n * HDIM + c0] = v;
      } else {
#pragma unroll
        for (int j = 0; j < 8; ++j) v[j] = 0;
      }
      *(short8*)&Xt[row * LDP + c0] = v;
    }
  }
  __syncthreads();

  const int l = t & 63;
  const int w = t >> 6;
  const int lr = l & 15;
  const int lg = l >> 4;
  const int aoff = lr * LDP + lg * 8;
  const int na = w * 32 + lr, nb = na + 16;

  const f32x4 zero4 = {0.f, 0.f, 0.f, 0.f};
  f32x4 ap_[4][2], ac_[4][2];
#pragma unroll
  for (int mi = 0; mi < 4; ++mi) {
    ap_[mi][0] = zero4; ap_[mi][1] = zero4;
    ac_[mi][0] = zero4; ac_[mi][1] = zero4;
  }

  const short* wpA = wp_t + na * HDIM + lg * 8;
  const short* wpB = wp_t + nb * HDIM + lg * 8;
  const short* wcA = wc_t + na * HDIM + lg * 8;
  const short* wcB = wc_t + nb * HDIM + lg * 8;

#pragma unroll
  for (int kk = 0; kk < 4; ++kk) {
    short8 b10 = *(const short8*)(wpA + kk * 32);
    short8 b11 = *(const short8*)(wpB + kk * 32);
    short8 b20 = *(const short8*)(wcA + kk * 32);
    short8 b21 = *(const short8*)(wcB + kk * 32);
#pragma unroll
    for (int mi = 0; mi < 4; ++mi) {
      short8 a8 = *(const short8*)&Xt[mi * 16 * LDP + aoff + kk * 32];
      ap_[mi][0] = __builtin_amdgcn_mfma_f32_16x16x32_bf16(a8, b10, ap_[mi][0], 0, 0, 0);
      ap_[mi][1] = __builtin_amdgcn_mfma_f32_16x16x32_bf16(a8, b11, ap_[mi][1], 0, 0, 0);
      ac_[mi][0] = __builtin_amdgcn_mfma_f32_16x16x32_bf16(a8, b20, ac_[mi][0], 0, 0, 0);
      ac_[mi][1] = __builtin_amdgcn_mfma_f32_16x16x32_bf16(a8, b21, ac_[mi][1], 0, 0, 0);
    }
  }

  {
    const float bpa = b_p[na], bpb = b_p[nb];
    const float bca = b_c[na], bcb = b_c[nb];
#pragma unroll
    for (int mi = 0; mi < 4; ++mi) {
#pragma unroll
      for (int r = 0; r < 4; ++r) {
        const int m = mi * 16 + lg * 4 + r;
        float v0 = ap_[mi][0][r] + bpa; v0 = v0 > 0.f ? v0 : 0.01f * v0;
        float v1 = ap_[mi][1][r] + bpb; v1 = v1 > 0.f ? v1 : 0.01f * v1;
        float u0 = ac_[mi][0][r] + bca; u0 = u0 > 0.f ? u0 : 0.01f * u0;
        float u1 = ac_[mi][1][r] + bcb; u1 = u1 > 0.f ? u1 : 0.01f * u1;
        Yp[m * LDP + na] = f2bf(v0);
        Yp[m * LDP + nb] = f2bf(v1);
        Yc[m * LDP + na] = f2bf(u0);
        Yc[m * LDP + nb] = f2bf(u1);
      }
    }
  }
  __syncthreads();

  f32x4 aa_[4][2], ab_[4][2];
#pragma unroll
  for (int mi = 0; mi < 4; ++mi) {
    aa_[mi][0] = zero4; aa_[mi][1] = zero4;
    ab_[mi][0] = zero4; ab_[mi][1] = zero4;
  }
  const short* w1Aa = w1_t + na * (3 * HDIM) + lg * 8;
  const short* w1Ab = w1_t + nb * (3 * HDIM) + lg * 8;
#pragma unroll
  for (int kk = 0; kk < 4; ++kk) {
    short8 ba0 = *(const short8*)(w1Aa + kk * 32);
    short8 ba1 = *(const short8*)(w1Ab + kk * 32);
    short8 bb0 = *(const short8*)(w1Aa + HDIM + kk * 32);
    short8 bb1 = *(const short8*)(w1Ab + HDIM + kk * 32);
#pragma unroll
    for (int mi = 0; mi < 4; ++mi) {
      short8 ayp = *(const short8*)&Yp[mi * 16 * LDP + aoff + kk * 32];
      short8 ayc = *(const short8*)&Yc[mi * 16 * LDP + aoff + kk * 32];
      aa_[mi][0] = __builtin_amdgcn_mfma_f32_16x16x32_bf16(ayp, ba0, aa_[mi][0], 0, 0, 0);
      aa_[mi][1] = __builtin_amdgcn_mfma_f32_16x16x32_bf16(ayp, ba1, aa_[mi][1], 0, 0, 0);
      ab_[mi][0] = __builtin_amdgcn_mfma_f32_16x16x32_bf16(ayc, bb0, ab_[mi][0], 0, 0, 0);
      ab_[mi][1] = __builtin_amdgcn_mfma_f32_16x16x32_bf16(ayc, bb1, ab_[mi][1], 0, 0, 0);
    }
  }

  {
    const float b1a = b1[na], b1b = b1[nb];
#pragma unroll
    for (int mi = 0; mi < 4; ++mi) {
#pragma unroll
      for (int r = 0; r < 4; ++r) {
        const int m = mi * 16 + lg * 4 + r;
        const int n = n0 + m;
        if (n < N_NODES) {
          Abuf[(size_t)n * HDIM + na] = f2bf(aa_[mi][0][r] + b1a);
          Abuf[(size_t)n * HDIM + nb] = f2bf(aa_[mi][1][r] + b1b);
          Bbuf[(size_t)n * HDIM + na] = f2bf(ab_[mi][0][r]);
          Bbuf[(size_t)n * HDIM + nb] = f2bf(ab_[mi][1][r]);
        }
      }
    }
  }
}

// ---- k2: per-edge: h = relu(S + |x_s-x_d|@W1c); out = sigmoid(h.w2 + b2) ----
// perm (nullable): src-sorted edge permutation; XCD-swizzled blockIdx.
__global__ __launch_bounds__(512, 8) void edge_kernel(
    const int* __restrict__ ei, const int* __restrict__ perm,
    const short* __restrict__ x_bf, const short* __restrict__ Abuf,
    const short* __restrict__ Bbuf, const short* __restrict__ w1_t,
    const float* __restrict__ w2v, const float* __restrict__ b2,
    float* __restrict__ out, int nblocks) {
  __shared__ __align__(16) short Dt[BM * LDP];
  __shared__ __align__(16) short St[BM * LDP];
  __shared__ float partial[8][BM];
  __shared__ int eidS[BM];

  // bijective XCD swizzle (m204): contiguous grid chunk per XCD
  int bid = blockIdx.x;
  {
    const int nx = 8;
    const int q = nblocks / nx, r = nblocks % nx;
    const int xcd = bid % nx, idx = bid / nx;
    bid = (xcd < r ? xcd * (q + 1) : r * (q + 1) + (xcd - r) * q) + idx;
  }
  const int t = threadIdx.x;
  const int e0 = bid * BM;

  {
    const int lane16 = t & 15, rq = t >> 4, c0 = lane16 * 8;
#pragma unroll
    for (int pass = 0; pass < 2; ++pass) {
      const int row = pass * 32 + rq;
      const int eidx = perm ? perm[e0 + row] : (e0 + row);
      eidS[row] = eidx;
      const int s = ei[eidx];
      const int d = ei[E_EDGES + eidx];
      short8 p8 = *(const short8*)(x_bf + (size_t)s * HDIM + c0);
      short8 c8 = *(const short8*)(x_bf + (size_t)d * HDIM + c0);
      short8 a8 = *(const short8*)(Abuf + (size_t)s * HDIM + c0);
      short8 b8 = *(const short8*)(Bbuf + (size_t)d * HDIM + c0);
      float df[8], sf[8];
#pragma unroll
      for (int j = 0; j < 8; ++j) {
        df[j] = fabsf(bf2f(p8[j]) - bf2f(c8[j]));
        sf[j] = bf2f(a8[j]) + bf2f(b8[j]);
      }
      uint4 vd, vs;
      vd.x = pack_bf16_rn(df[0], df[1]);
      vd.y = pack_bf16_rn(df[2], df[3]);
      vd.z = pack_bf16_rn(df[4], df[5]);
      vd.w = pack_bf16_rn(df[6], df[7]);
      vs.x = pack_bf16_rn(sf[0], sf[1]);
      vs.y = pack_bf16_rn(sf[2], sf[3]);
      vs.z = pack_bf16_rn(sf[4], sf[5]);
      vs.w = pack_bf16_rn(sf[6], sf[7]);
      *(uint4*)&Dt[row * LDP + c0] = vd;
      *(uint4*)&St[row * LDP + c0] = vs;
    }
  }
  __syncthreads();

  const int l = t & 63;
  const int w = t >> 6;
  const int lr = l & 15;
  const int lg = l >> 4;
  const int na = w * 16 + lr;
  const int aoff = lr * LDP + lg * 8;

  f32x4 acc[4];
#pragma unroll
  for (int mi = 0; mi < 4; ++mi) {
#pragma unroll
    for (int r = 0; r < 4; ++r) {
      acc[mi][r] = bf2f(St[(mi * 16 + lg * 4 + r) * LDP + na]);
    }
  }

  const short* w1D = w1_t + na * (3 * HDIM) + 2 * HDIM + lg * 8;
#pragma unroll
  for (int kk = 0; kk < 4; ++kk) {
    short8 b8 = *(const short8*)(w1D + kk * 32);
#pragma unroll
    for (int mi = 0; mi < 4; ++mi) {
      short8 a8 = *(const short8*)&Dt[mi * 16 * LDP + aoff + kk * 32];
      acc[mi] = __builtin_amdgcn_mfma_f32_16x16x32_bf16(a8, b8, acc[mi], 0, 0, 0);
    }
  }

  {
    const float w2a = w2v[na];
#pragma unroll
    for (int mi = 0; mi < 4; ++mi) {
#pragma unroll
      for (int r = 0; r < 4; ++r) {
        float h = acc[mi][r] > 0.f ? acc[mi][r] : 0.f;
        float v = h * w2a;
        v += __shfl_xor(v, 1);
        v += __shfl_xor(v, 2);
        v += __shfl_xor(v, 4);
        v += __shfl_xor(v, 8);
        if (lr == 0) partial[w][mi * 16 + lg * 4 + r] = v;
      }
    }
  }
  __syncthreads();

  if (t < BM) {
    float z = partial[0][t] + partial[1][t] + partial[2][t] + partial[3][t] +
              partial[4][t] + partial[5][t] + partial[6][t] + partial[7][t] + b2[0];
    out[eidS[t]] = 1.0f / (1.0f + __expf(-z));
  }
}

// ---- fallback (validated v2 path) if workspace is too small ----
__global__ __launch_bounds__(512, 4) void edge_weight_fallback(
    const float* __restrict__ x, const int* __restrict__ ei,
    const float* __restrict__ b_p, const float* __restrict__ b_c,
    const float* __restrict__ b1, const float* __restrict__ b2,
    const short* __restrict__ wp_t, const short* __restrict__ wc_t,
    const short* __restrict__ w1_t, const float* __restrict__ w2v,
    float* __restrict__ out) {
  __shared__ __align__(16) short Pt[BM * LDP];
  __shared__ __align__(16) short Ct[BM * LDP];
  __shared__ __align__(16) short Dt[BM * LDP];
  __shared__ float partial[8][BM];

  const int t = threadIdx.x;
  const int e0 = blockIdx.x * BM;
  {
    const int lane16 = t & 15, rq = t >> 4, c0 = lane16 * 8;
#pragma unroll
    for (int pass = 0; pass < 2; ++pass) {
      const int row = pass * 32 + rq;
      const int ip = ei[e0 + row];
      const int ic = ei[E_EDGES + e0 + row];
      const float* ps = x + (size_t)ip * HDIM + c0;
      const float* cs = x + (size_t)ic * HDIM + c0;
      float4 pa = *(const float4*)ps, pb = *(const float4*)(ps + 4);
      float4 ca = *(const float4*)cs, cb = *(const float4*)(cs + 4);
      float pf[8] = {pa.x, pa.y, pa.z, pa.w, pb.x, pb.y, pb.z, pb.w};
      float cf[8] = {ca.x, ca.y, ca.z, ca.w, cb.x, cb.y, cb.z, cb.w};
      short8 vp, vc, vd;
#pragma unroll
      for (int j = 0; j < 8; ++j) {
        vp[j] = f2bf(pf[j]); vc[j] = f2bf(cf[j]); vd[j] = f2bf(fabsf(pf[j] - cf[j]));
      }
      *(short8*)&Pt[row * LDP + c0] = vp;
      *(short8*)&Ct[row * LDP + c0] = vc;
      *(short8*)&Dt[row * LDP + c0] = vd;
    }
  }
  __syncthreads();
  const int l = t & 63, w = t >> 6, lr = l & 15, lg = l >> 4;
  const int n0 = w * 16, na = n0 + lr, aoff = lr * LDP + lg * 8;
  const f32x4 zero4 = {0.f, 0.f, 0.f, 0.f};
  f32x4 acc1[4], acc2[4], acc3[4];
#pragma unroll
  for (int mi = 0; mi < 4; ++mi) { acc1[mi] = zero4; acc2[mi] = zero4; acc3[mi] = zero4; }
  const short* wpA = wp_t + na * HDIM + lg * 8;
  const short* wcA = wc_t + na * HDIM + lg * 8;
  const short* w1A = w1_t + na * (3 * HDIM) + lg * 8;
#pragma unroll
  for (int kk = 0; kk < 4; ++kk) {
    short8 bp8 = *(const short8*)(wpA + kk * 32);
    short8 bc8 = *(const short8*)(wcA + kk * 32);
    short8 bd8 = *(const short8*)(w1A + 2 * HDIM + kk * 32);
#pragma unroll
    for (int mi = 0; mi < 4; ++mi) {
      short8 ap = *(const short8*)&Pt[mi * 16 * LDP + aoff + kk * 32];
      short8 ac = *(const short8*)&Ct[mi * 16 * LDP + aoff + kk * 32];
      short8 ad = *(const short8*)&Dt[mi * 16 * LDP + aoff + kk * 32];
      acc1[mi] = __builtin_amdgcn_mfma_f32_16x16x32_bf16(ap, bp8, acc1[mi], 0, 0, 0);
      acc2[mi] = __builtin_amdgcn_mfma_f32_16x16x32_bf16(ac, bc8, acc2[mi], 0, 0, 0);
      acc3[mi] = __builtin_amdgcn_mfma_f32_16x16x32_bf16(ad, bd8, acc3[mi], 0, 0, 0);
    }
  }
  __syncthreads();
  {
    const float bpa = b_p[na], bca = b_c[na];
#pragma unroll
    for (int mi = 0; mi < 4; ++mi) {
#pragma unroll
      for (int r = 0; r < 4; ++r) {
        const int m = mi * 16 + lg * 4 + r;
        float v0 = acc1[mi][r] + bpa; v0 = v0 > 0.f ? v0 : 0.01f * v0;
        float u0 = acc2[mi][r] + bca; u0 = u0 > 0.f ? u0 : 0.01f * u0;
        Pt[m * LDP + na] = f2bf(v0);
        Ct[m * LDP + na] = f2bf(u0);
      }
    }
  }
  __syncthreads();
#pragma unroll
  for (int kk = 0; kk < 4; ++kk) {
    short8 b0 = *(const short8*)(w1A + kk * 32);
    short8 b1f = *(const short8*)(w1A + HDIM + kk * 32);
#pragma unroll
    for (int mi = 0; mi < 4; ++mi) {
      short8 a0 = *(const short8*)&Pt[mi * 16 * LDP + aoff + kk * 32];
      short8 a1 = *(const short8*)&Ct[mi * 16 * LDP + aoff + kk * 32];
      acc3[mi] = __builtin_amdgcn_mfma_f32_16x16x32_bf16(a0, b0, acc3[mi], 0, 0, 0);
      acc3[mi] = __builtin_amdgcn_mfma_f32_16x16x32_bf16(a1, b1f, acc3[mi], 0, 0, 0);
    }
  }
  {
    const float b1a = b1[na], w2a = w2v[na];
#pragma unroll
    for (int mi = 0; mi < 4; ++mi) {
#pragma unroll
      for (int r = 0; r < 4; ++r) {
        float h0 = acc3[mi][r] + b1a; h0 = h0 > 0.f ? h0 : 0.f;
        float v = h0 * w2a;
        v += __shfl_xor(v, 1); v += __shfl_xor(v, 2);
        v += __shfl_xor(v, 4); v += __shfl_xor(v, 8);
        if (lr == 0) partial[w][mi * 16 + lg * 4 + r] = v;
      }
    }
  }
  __syncthreads();
  if (t < BM) {
    float z = partial[0][t] + partial[1][t] + partial[2][t] + partial[3][t] +
              partial[4][t] + partial[5][t] + partial[6][t] + partial[7][t] + b2[0];
    out[e0 + t] = 1.0f / (1.0f + __expf(-z));
  }
}

extern "C" void kernel_launch(void* const* d_in, const int* in_sizes, int n_in,
                              void* d_out, int out_size, void* d_ws, size_t ws_size,
                              hipStream_t stream) {
  const float* x  = (const float*)d_in[0];
  const int*   ei = (const int*)d_in[1];
  const float* Wp = (const float*)d_in[2];
  const float* bp = (const float*)d_in[3];
  const float* Wc = (const float*)d_in[4];
  const float* bc = (const float*)d_in[5];
  const float* W1 = (const float*)d_in[6];
  const float* b1 = (const float*)d_in[7];
  const float* W2 = (const float*)d_in[8];
  const float* b2 = (const float*)d_in[9];
  float* out = (float*)d_out;

  short* wp_t = (short*)d_ws;
  short* wc_t = wp_t + HDIM * HDIM;
  short* w1_t = wc_t + HDIM * HDIM;
  float* w2v  = (float*)(w1_t + HDIM * 3 * HDIM);
  short* x_bf = (short*)(w2v + HDIM);
  short* Abuf = x_bf + (size_t)N_NODES * HDIM;
  short* Bbuf = Abuf + (size_t)N_NODES * HDIM;
  int*   hist = (int*)(Bbuf + (size_t)N_NODES * HDIM);
  int*   cursor = hist + NB;
  int*   perm = cursor + NB;

  const size_t needed_tables = (size_t)((char*)hist - (char*)d_ws);
  const size_t needed_sort   = (size_t)((char*)(perm + E_EDGES) - (char*)d_ws);
  const int nblocks = E_EDGES / BM;

  prep_weights<<<(HDIM * 3 * HDIM + 255) / 256, 256, 0, stream>>>(Wp, Wc, W1, W2,
                                                                  wp_t, wc_t, w1_t, w2v);
  if (ws_size >= needed_tables) {
    node_precompute<<<(N_NODES + BM - 1) / BM, 256, 0, stream>>>(
        x, bp, bc, b1, wp_t, wc_t, w1_t, x_bf, Abuf, Bbuf);
    const int* perm_arg = nullptr;
    if (ws_size >= needed_sort) {
      hipMemsetAsync(hist, 0, NB * sizeof(int), stream);
      hist_kernel<<<(E_EDGES + 2047) / 2048, 512, 0, stream>>>(ei, hist);
      scan_kernel<<<1, NB, 0, stream>>>(hist, cursor);
      scatter_kernel<<<(E_EDGES + 511) / 512, 512, 0, stream>>>(ei, cursor, perm);
      perm_arg = perm;
    }
    edge_kernel<<<nblocks, 512, 0, stream>>>(ei, perm_arg, x_bf, Abuf, Bbuf,
                                             w1_t, w2v, b2, out, nblocks);
  } else {
    edge_weight_fallback<<<nblocks, 512, 0, stream>>>(x, ei, bp, bc, b1, b2,
                                                      wp_t, wc_t, w1_t, w2v, out);
  }
}

// Round 7
// 253.338 us; speedup vs baseline: 1.8695x; 1.8695x over previous
//
#include <hip/hip_runtime.h>
#include <hip/hip_bf16.h>

#define E_EDGES 1000000
#define N_NODES 100000
#define HDIM 128
#define BM 64
#define LDP 136   // padded LDS row stride for bf16 tiles
#define NB 1024   // src buckets (src>>7 -> 0..781)
#define EPB 16384 // edges per sort block
#define NBLK ((E_EDGES + EPB - 1) / EPB)  // 62

typedef __attribute__((ext_vector_type(8))) short short8;
typedef __attribute__((ext_vector_type(4))) float f32x4;

static __device__ __forceinline__ short f2bf(float f) {
  unsigned int u = __float_as_uint(f);
  unsigned int r = (u + 0x7FFFu + ((u >> 16) & 1u)) >> 16;
  return (short)r;
}
static __device__ __forceinline__ float bf2f(short s) {
  return __uint_as_float(((unsigned int)(unsigned short)s) << 16);
}
static __device__ __forceinline__ unsigned int pack_bf16_rn(float lo, float hi) {
  __hip_bfloat162 h = __float22bfloat162_rn(make_float2(lo, hi));
  unsigned int u;
  __builtin_memcpy(&u, &h, 4);
  return u;
}

// ---- k0: transpose + bf16-ize weights: Wt[out][in] row-major ----
__global__ void prep_weights(const float* __restrict__ Wp, const float* __restrict__ Wc,
                             const float* __restrict__ W1, const float* __restrict__ W2,
                             short* __restrict__ wp_t, short* __restrict__ wc_t,
                             short* __restrict__ w1_t, float* __restrict__ w2v) {
  int i = blockIdx.x * 256 + threadIdx.x;
  if (i < HDIM * HDIM) {
    int o = i >> 7, k = i & (HDIM - 1);
    wp_t[i] = f2bf(Wp[k * HDIM + o]);
    wc_t[i] = f2bf(Wc[k * HDIM + o]);
  }
  if (i < HDIM * 3 * HDIM) {
    int o = i / (3 * HDIM), k = i - o * (3 * HDIM);
    w1_t[i] = f2bf(W1[k * HDIM + o]);
  }
  if (i < HDIM) w2v[i] = W2[i];
}

// ---- two-level counting sort by src>>7 (no global atomics, deterministic bases) ----
__global__ __launch_bounds__(512) void hist2_kernel(const int* __restrict__ ei,
                                                    int* __restrict__ hist2) {
  __shared__ int h[NB];
  const int t = threadIdx.x;
  h[t] = 0; h[t + 512] = 0;
  __syncthreads();
  const int base = blockIdx.x * EPB;
#pragma unroll
  for (int i = 0; i < EPB / 512; ++i) {
    int e = base + i * 512 + t;
    if (e < E_EDGES) atomicAdd(&h[ei[e] >> 7], 1);
  }
  __syncthreads();
  hist2[blockIdx.x * NB + t] = h[t];
  hist2[blockIdx.x * NB + t + 512] = h[t + 512];
}

__global__ __launch_bounds__(1024) void scan2_kernel(const int* __restrict__ hist2,
                                                     int* __restrict__ base2) {
  __shared__ int s[NB];
  const int t = threadIdx.x;
  int col = 0;
  for (int blk = 0; blk < NBLK; ++blk) col += hist2[blk * NB + t];
  s[t] = col;
  __syncthreads();
  for (int off = 1; off < NB; off <<= 1) {
    int v = (t >= off) ? s[t - off] : 0;
    __syncthreads();
    s[t] += v;
    __syncthreads();
  }
  int running = s[t] - col;  // exclusive bucket prefix
  for (int blk = 0; blk < NBLK; ++blk) {
    base2[blk * NB + t] = running;
    running += hist2[blk * NB + t];
  }
}

__global__ __launch_bounds__(512) void scatter2_kernel(const int* __restrict__ ei,
                                                       const int* __restrict__ base2,
                                                       int* __restrict__ perm) {
  __shared__ int lc[NB];
  __shared__ int bb[NB];
  const int t = threadIdx.x;
  lc[t] = 0; lc[t + 512] = 0;
  bb[t] = base2[blockIdx.x * NB + t];
  bb[t + 512] = base2[blockIdx.x * NB + t + 512];
  __syncthreads();
  const int base = blockIdx.x * EPB;
#pragma unroll
  for (int i = 0; i < EPB / 512; ++i) {
    int e = base + i * 512 + t;
    if (e < E_EDGES) {
      int b = ei[e] >> 7;
      int r = atomicAdd(&lc[b], 1);
      perm[bb[b] + r] = e;
    }
  }
}

// ---- k1: per-node precompute ----
__global__ __launch_bounds__(256) void node_precompute(
    const float* __restrict__ x, const float* __restrict__ b_p,
    const float* __restrict__ b_c, const float* __restrict__ b1,
    const short* __restrict__ wp_t, const short* __restrict__ wc_t,
    const short* __restrict__ w1_t,
    short* __restrict__ x_bf, short* __restrict__ Abuf, short* __restrict__ Bbuf) {
  __shared__ __align__(16) short Xt[BM * LDP];
  __shared__ __align__(16) short Yp[BM * LDP];
  __shared__ __align__(16) short Yc[BM * LDP];

  const int t = threadIdx.x;
  const int n0 = blockIdx.x * BM;

  {
    const int lane16 = t & 15, rq = t >> 4, c0 = lane16 * 8;
#pragma unroll
    for (int pass = 0; pass < 4; ++pass) {
      const int row = pass * 16 + rq;
      const int n = n0 + row;
      short8 v;
      if (n < N_NODES) {
        const float* ps = x + (size_t)n * HDIM + c0;
        float4 a = *(const float4*)ps;
        float4 b = *(const float4*)(ps + 4);
        float f[8] = {a.x, a.y, a.z, a.w, b.x, b.y, b.z, b.w};
#pragma unroll
        for (int j = 0; j < 8; ++j) v[j] = f2bf(f[j]);
        *(short8*)&x_bf[(size_t)n * HDIM + c0] = v;
      } else {
#pragma unroll
        for (int j = 0; j < 8; ++j) v[j] = 0;
      }
      *(short8*)&Xt[row * LDP + c0] = v;
    }
  }
  __syncthreads();

  const int l = t & 63;
  const int w = t >> 6;
  const int lr = l & 15;
  const int lg = l >> 4;
  const int aoff = lr * LDP + lg * 8;
  const int na = w * 32 + lr, nb = na + 16;

  const f32x4 zero4 = {0.f, 0.f, 0.f, 0.f};
  f32x4 ap_[4][2], ac_[4][2];
#pragma unroll
  for (int mi = 0; mi < 4; ++mi) {
    ap_[mi][0] = zero4; ap_[mi][1] = zero4;
    ac_[mi][0] = zero4; ac_[mi][1] = zero4;
  }

  const short* wpA = wp_t + na * HDIM + lg * 8;
  const short* wpB = wp_t + nb * HDIM + lg * 8;
  const short* wcA = wc_t + na * HDIM + lg * 8;
  const short* wcB = wc_t + nb * HDIM + lg * 8;

#pragma unroll
  for (int kk = 0; kk < 4; ++kk) {
    short8 b10 = *(const short8*)(wpA + kk * 32);
    short8 b11 = *(const short8*)(wpB + kk * 32);
    short8 b20 = *(const short8*)(wcA + kk * 32);
    short8 b21 = *(const short8*)(wcB + kk * 32);
#pragma unroll
    for (int mi = 0; mi < 4; ++mi) {
      short8 a8 = *(const short8*)&Xt[mi * 16 * LDP + aoff + kk * 32];
      ap_[mi][0] = __builtin_amdgcn_mfma_f32_16x16x32_bf16(a8, b10, ap_[mi][0], 0, 0, 0);
      ap_[mi][1] = __builtin_amdgcn_mfma_f32_16x16x32_bf16(a8, b11, ap_[mi][1], 0, 0, 0);
      ac_[mi][0] = __builtin_amdgcn_mfma_f32_16x16x32_bf16(a8, b20, ac_[mi][0], 0, 0, 0);
      ac_[mi][1] = __builtin_amdgcn_mfma_f32_16x16x32_bf16(a8, b21, ac_[mi][1], 0, 0, 0);
    }
  }

  {
    const float bpa = b_p[na], bpb = b_p[nb];
    const float bca = b_c[na], bcb = b_c[nb];
#pragma unroll
    for (int mi = 0; mi < 4; ++mi) {
#pragma unroll
      for (int r = 0; r < 4; ++r) {
        const int m = mi * 16 + lg * 4 + r;
        float v0 = ap_[mi][0][r] + bpa; v0 = v0 > 0.f ? v0 : 0.01f * v0;
        float v1 = ap_[mi][1][r] + bpb; v1 = v1 > 0.f ? v1 : 0.01f * v1;
        float u0 = ac_[mi][0][r] + bca; u0 = u0 > 0.f ? u0 : 0.01f * u0;
        float u1 = ac_[mi][1][r] + bcb; u1 = u1 > 0.f ? u1 : 0.01f * u1;
        Yp[m * LDP + na] = f2bf(v0);
        Yp[m * LDP + nb] = f2bf(v1);
        Yc[m * LDP + na] = f2bf(u0);
        Yc[m * LDP + nb] = f2bf(u1);
      }
    }
  }
  __syncthreads();

  f32x4 aa_[4][2], ab_[4][2];
#pragma unroll
  for (int mi = 0; mi < 4; ++mi) {
    aa_[mi][0] = zero4; aa_[mi][1] = zero4;
    ab_[mi][0] = zero4; ab_[mi][1] = zero4;
  }
  const short* w1Aa = w1_t + na * (3 * HDIM) + lg * 8;
  const short* w1Ab = w1_t + nb * (3 * HDIM) + lg * 8;
#pragma unroll
  for (int kk = 0; kk < 4; ++kk) {
    short8 ba0 = *(const short8*)(w1Aa + kk * 32);
    short8 ba1 = *(const short8*)(w1Ab + kk * 32);
    short8 bb0 = *(const short8*)(w1Aa + HDIM + kk * 32);
    short8 bb1 = *(const short8*)(w1Ab + HDIM + kk * 32);
#pragma unroll
    for (int mi = 0; mi < 4; ++mi) {
      short8 ayp = *(const short8*)&Yp[mi * 16 * LDP + aoff + kk * 32];
      short8 ayc = *(const short8*)&Yc[mi * 16 * LDP + aoff + kk * 32];
      aa_[mi][0] = __builtin_amdgcn_mfma_f32_16x16x32_bf16(ayp, ba0, aa_[mi][0], 0, 0, 0);
      aa_[mi][1] = __builtin_amdgcn_mfma_f32_16x16x32_bf16(ayp, ba1, aa_[mi][1], 0, 0, 0);
      ab_[mi][0] = __builtin_amdgcn_mfma_f32_16x16x32_bf16(ayc, bb0, ab_[mi][0], 0, 0, 0);
      ab_[mi][1] = __builtin_amdgcn_mfma_f32_16x16x32_bf16(ayc, bb1, ab_[mi][1], 0, 0, 0);
    }
  }

  {
    const float b1a = b1[na], b1b = b1[nb];
#pragma unroll
    for (int mi = 0; mi < 4; ++mi) {
#pragma unroll
      for (int r = 0; r < 4; ++r) {
        const int m = mi * 16 + lg * 4 + r;
        const int n = n0 + m;
        if (n < N_NODES) {
          Abuf[(size_t)n * HDIM + na] = f2bf(aa_[mi][0][r] + b1a);
          Abuf[(size_t)n * HDIM + nb] = f2bf(aa_[mi][1][r] + b1b);
          Bbuf[(size_t)n * HDIM + na] = f2bf(ab_[mi][0][r]);
          Bbuf[(size_t)n * HDIM + nb] = f2bf(ab_[mi][1][r]);
        }
      }
    }
  }
}

// ---- k2: per-edge: h = relu(S + |x_s-x_d|@W1c); out = sigmoid(h.w2 + b2) ----
__global__ __launch_bounds__(512, 8) void edge_kernel(
    const int* __restrict__ ei, const int* __restrict__ perm,
    const short* __restrict__ x_bf, const short* __restrict__ Abuf,
    const short* __restrict__ Bbuf, const short* __restrict__ w1_t,
    const float* __restrict__ w2v, const float* __restrict__ b2,
    float* __restrict__ out, int nblocks) {
  __shared__ __align__(16) short Dt[BM * LDP];
  __shared__ __align__(16) short St[BM * LDP];
  __shared__ float partial[8][BM];
  __shared__ int eidS[BM];

  // bijective XCD swizzle (m204): contiguous grid chunk per XCD
  int bid = blockIdx.x;
  {
    const int nx = 8;
    const int q = nblocks / nx, r = nblocks % nx;
    const int xcd = bid % nx, idx = bid / nx;
    bid = (xcd < r ? xcd * (q + 1) : r * (q + 1) + (xcd - r) * q) + idx;
  }
  const int t = threadIdx.x;
  const int e0 = bid * BM;

  {
    const int lane16 = t & 15, rq = t >> 4, c0 = lane16 * 8;
#pragma unroll
    for (int pass = 0; pass < 2; ++pass) {
      const int row = pass * 32 + rq;
      const int eidx = perm ? perm[e0 + row] : (e0 + row);
      eidS[row] = eidx;
      const int s = ei[eidx];
      const int d = ei[E_EDGES + eidx];
      short8 p8 = *(const short8*)(x_bf + (size_t)s * HDIM + c0);
      short8 c8 = *(const short8*)(x_bf + (size_t)d * HDIM + c0);
      short8 a8 = *(const short8*)(Abuf + (size_t)s * HDIM + c0);
      short8 b8 = *(const short8*)(Bbuf + (size_t)d * HDIM + c0);
      float df[8], sf[8];
#pragma unroll
      for (int j = 0; j < 8; ++j) {
        df[j] = fabsf(bf2f(p8[j]) - bf2f(c8[j]));
        sf[j] = bf2f(a8[j]) + bf2f(b8[j]);
      }
      uint4 vd, vs;
      vd.x = pack_bf16_rn(df[0], df[1]);
      vd.y = pack_bf16_rn(df[2], df[3]);
      vd.z = pack_bf16_rn(df[4], df[5]);
      vd.w = pack_bf16_rn(df[6], df[7]);
      vs.x = pack_bf16_rn(sf[0], sf[1]);
      vs.y = pack_bf16_rn(sf[2], sf[3]);
      vs.z = pack_bf16_rn(sf[4], sf[5]);
      vs.w = pack_bf16_rn(sf[6], sf[7]);
      *(uint4*)&Dt[row * LDP + c0] = vd;
      *(uint4*)&St[row * LDP + c0] = vs;
    }
  }
  __syncthreads();

  const int l = t & 63;
  const int w = t >> 6;
  const int lr = l & 15;
  const int lg = l >> 4;
  const int na = w * 16 + lr;
  const int aoff = lr * LDP + lg * 8;

  f32x4 acc[4];
#pragma unroll
  for (int mi = 0; mi < 4; ++mi) {
#pragma unroll
    for (int r = 0; r < 4; ++r) {
      acc[mi][r] = bf2f(St[(mi * 16 + lg * 4 + r) * LDP + na]);
    }
  }

  const short* w1D = w1_t + na * (3 * HDIM) + 2 * HDIM + lg * 8;
#pragma unroll
  for (int kk = 0; kk < 4; ++kk) {
    short8 b8 = *(const short8*)(w1D + kk * 32);
#pragma unroll
    for (int mi = 0; mi < 4; ++mi) {
      short8 a8 = *(const short8*)&Dt[mi * 16 * LDP + aoff + kk * 32];
      acc[mi] = __builtin_amdgcn_mfma_f32_16x16x32_bf16(a8, b8, acc[mi], 0, 0, 0);
    }
  }

  {
    const float w2a = w2v[na];
#pragma unroll
    for (int mi = 0; mi < 4; ++mi) {
#pragma unroll
      for (int r = 0; r < 4; ++r) {
        float h = acc[mi][r] > 0.f ? acc[mi][r] : 0.f;
        float v = h * w2a;
        v += __shfl_xor(v, 1);
        v += __shfl_xor(v, 2);
        v += __shfl_xor(v, 4);
        v += __shfl_xor(v, 8);
        if (lr == 0) partial[w][mi * 16 + lg * 4 + r] = v;
      }
    }
  }
  __syncthreads();

  if (t < BM) {
    float z = partial[0][t] + partial[1][t] + partial[2][t] + partial[3][t] +
              partial[4][t] + partial[5][t] + partial[6][t] + partial[7][t] + b2[0];
    out[eidS[t]] = 1.0f / (1.0f + __expf(-z));
  }
}

// ---- fallback (validated v2 path) if workspace is too small ----
__global__ __launch_bounds__(512, 4) void edge_weight_fallback(
    const float* __restrict__ x, const int* __restrict__ ei,
    const float* __restrict__ b_p, const float* __restrict__ b_c,
    const float* __restrict__ b1, const float* __restrict__ b2,
    const short* __restrict__ wp_t, const short* __restrict__ wc_t,
    const short* __restrict__ w1_t, const float* __restrict__ w2v,
    float* __restrict__ out) {
  __shared__ __align__(16) short Pt[BM * LDP];
  __shared__ __align__(16) short Ct[BM * LDP];
  __shared__ __align__(16) short Dt[BM * LDP];
  __shared__ float partial[8][BM];

  const int t = threadIdx.x;
  const int e0 = blockIdx.x * BM;
  {
    const int lane16 = t & 15, rq = t >> 4, c0 = lane16 * 8;
#pragma unroll
    for (int pass = 0; pass < 2; ++pass) {
      const int row = pass * 32 + rq;
      const int ip = ei[e0 + row];
      const int ic = ei[E_EDGES + e0 + row];
      const float* ps = x + (size_t)ip * HDIM + c0;
      const float* cs = x + (size_t)ic * HDIM + c0;
      float4 pa = *(const float4*)ps, pb = *(const float4*)(ps + 4);
      float4 ca = *(const float4*)cs, cb = *(const float4*)(cs + 4);
      float pf[8] = {pa.x, pa.y, pa.z, pa.w, pb.x, pb.y, pb.z, pb.w};
      float cf[8] = {ca.x, ca.y, ca.z, ca.w, cb.x, cb.y, cb.z, cb.w};
      short8 vp, vc, vd;
#pragma unroll
      for (int j = 0; j < 8; ++j) {
        vp[j] = f2bf(pf[j]); vc[j] = f2bf(cf[j]); vd[j] = f2bf(fabsf(pf[j] - cf[j]));
      }
      *(short8*)&Pt[row * LDP + c0] = vp;
      *(short8*)&Ct[row * LDP + c0] = vc;
      *(short8*)&Dt[row * LDP + c0] = vd;
    }
  }
  __syncthreads();
  const int l = t & 63, w = t >> 6, lr = l & 15, lg = l >> 4;
  const int n0 = w * 16, na = n0 + lr, aoff = lr * LDP + lg * 8;
  const f32x4 zero4 = {0.f, 0.f, 0.f, 0.f};
  f32x4 acc1[4], acc2[4], acc3[4];
#pragma unroll
  for (int mi = 0; mi < 4; ++mi) { acc1[mi] = zero4; acc2[mi] = zero4; acc3[mi] = zero4; }
  const short* wpA = wp_t + na * HDIM + lg * 8;
  const short* wcA = wc_t + na * HDIM + lg * 8;
  const short* w1A = w1_t + na * (3 * HDIM) + lg * 8;
#pragma unroll
  for (int kk = 0; kk < 4; ++kk) {
    short8 bp8 = *(const short8*)(wpA + kk * 32);
    short8 bc8 = *(const short8*)(wcA + kk * 32);
    short8 bd8 = *(const short8*)(w1A + 2 * HDIM + kk * 32);
#pragma unroll
    for (int mi = 0; mi < 4; ++mi) {
      short8 ap = *(const short8*)&Pt[mi * 16 * LDP + aoff + kk * 32];
      short8 ac = *(const short8*)&Ct[mi * 16 * LDP + aoff + kk * 32];
      short8 ad = *(const short8*)&Dt[mi * 16 * LDP + aoff + kk * 32];
      acc1[mi] = __builtin_amdgcn_mfma_f32_16x16x32_bf16(ap, bp8, acc1[mi], 0, 0, 0);
      acc2[mi] = __builtin_amdgcn_mfma_f32_16x16x32_bf16(ac, bc8, acc2[mi], 0, 0, 0);
      acc3[mi] = __builtin_amdgcn_mfma_f32_16x16x32_bf16(ad, bd8, acc3[mi], 0, 0, 0);
    }
  }
  __syncthreads();
  {
    const float bpa = b_p[na], bca = b_c[na];
#pragma unroll
    for (int mi = 0; mi < 4; ++mi) {
#pragma unroll
      for (int r = 0; r < 4; ++r) {
        const int m = mi * 16 + lg * 4 + r;
        float v0 = acc1[mi][r] + bpa; v0 = v0 > 0.f ? v0 : 0.01f * v0;
        float u0 = acc2[mi][r] + bca; u0 = u0 > 0.f ? u0 : 0.01f * u0;
        Pt[m * LDP + na] = f2bf(v0);
        Ct[m * LDP + na] = f2bf(u0);
      }
    }
  }
  __syncthreads();
#pragma unroll
  for (int kk = 0; kk < 4; ++kk) {
    short8 b0 = *(const short8*)(w1A + kk * 32);
    short8 b1f = *(const short8*)(w1A + HDIM + kk * 32);
#pragma unroll
    for (int mi = 0; mi < 4; ++mi) {
      short8 a0 = *(const short8*)&Pt[mi * 16 * LDP + aoff + kk * 32];
      short8 a1 = *(const short8*)&Ct[mi * 16 * LDP + aoff + kk * 32];
      acc3[mi] = __builtin_amdgcn_mfma_f32_16x16x32_bf16(a0, b0, acc3[mi], 0, 0, 0);
      acc3[mi] = __builtin_amdgcn_mfma_f32_16x16x32_bf16(a1, b1f, acc3[mi], 0, 0, 0);
    }
  }
  {
    const float b1a = b1[na], w2a = w2v[na];
#pragma unroll
    for (int mi = 0; mi < 4; ++mi) {
#pragma unroll
      for (int r = 0; r < 4; ++r) {
        float h0 = acc3[mi][r] + b1a; h0 = h0 > 0.f ? h0 : 0.f;
        float v = h0 * w2a;
        v += __shfl_xor(v, 1); v += __shfl_xor(v, 2);
        v += __shfl_xor(v, 4); v += __shfl_xor(v, 8);
        if (lr == 0) partial[w][mi * 16 + lg * 4 + r] = v;
      }
    }
  }
  __syncthreads();
  if (t < BM) {
    float z = partial[0][t] + partial[1][t] + partial[2][t] + partial[3][t] +
              partial[4][t] + partial[5][t] + partial[6][t] + partial[7][t] + b2[0];
    out[e0 + t] = 1.0f / (1.0f + __expf(-z));
  }
}

extern "C" void kernel_launch(void* const* d_in, const int* in_sizes, int n_in,
                              void* d_out, int out_size, void* d_ws, size_t ws_size,
                              hipStream_t stream) {
  const float* x  = (const float*)d_in[0];
  const int*   ei = (const int*)d_in[1];
  const float* Wp = (const float*)d_in[2];
  const float* bp = (const float*)d_in[3];
  const float* Wc = (const float*)d_in[4];
  const float* bc = (const float*)d_in[5];
  const float* W1 = (const float*)d_in[6];
  const float* b1 = (const float*)d_in[7];
  const float* W2 = (const float*)d_in[8];
  const float* b2 = (const float*)d_in[9];
  float* out = (float*)d_out;

  short* wp_t = (short*)d_ws;
  short* wc_t = wp_t + HDIM * HDIM;
  short* w1_t = wc_t + HDIM * HDIM;
  float* w2v  = (float*)(w1_t + HDIM * 3 * HDIM);
  short* x_bf = (short*)(w2v + HDIM);
  short* Abuf = x_bf + (size_t)N_NODES * HDIM;
  short* Bbuf = Abuf + (size_t)N_NODES * HDIM;
  int*   perm  = (int*)(Bbuf + (size_t)N_NODES * HDIM);
  int*   hist2 = perm + E_EDGES;
  int*   base2 = hist2 + (size_t)NBLK * NB;

  const size_t needed_tables = (size_t)((char*)perm - (char*)d_ws);
  const size_t needed_sort   = (size_t)((char*)(base2 + (size_t)NBLK * NB) - (char*)d_ws);
  const int nblocks = E_EDGES / BM;

  prep_weights<<<(HDIM * 3 * HDIM + 255) / 256, 256, 0, stream>>>(Wp, Wc, W1, W2,
                                                                  wp_t, wc_t, w1_t, w2v);
  if (ws_size >= needed_tables) {
    node_precompute<<<(N_NODES + BM - 1) / BM, 256, 0, stream>>>(
        x, bp, bc, b1, wp_t, wc_t, w1_t, x_bf, Abuf, Bbuf);
    const int* perm_arg = nullptr;
    if (ws_size >= needed_sort) {
      hist2_kernel<<<NBLK, 512, 0, stream>>>(ei, hist2);
      scan2_kernel<<<1, NB, 0, stream>>>(hist2, base2);
      scatter2_kernel<<<NBLK, 512, 0, stream>>>(ei, base2, perm);
      perm_arg = perm;
    }
    edge_kernel<<<nblocks, 512, 0, stream>>>(ei, perm_arg, x_bf, Abuf, Bbuf,
                                             w1_t, w2v, b2, out, nblocks);
  } else {
    edge_weight_fallback<<<nblocks, 512, 0, stream>>>(x, ei, bp, bc, b1, b2,
                                                      wp_t, wc_t, w1_t, w2v, out);
  }
}

// Round 8
// 199.767 us; speedup vs baseline: 2.3709x; 1.2682x over previous
//
#include <hip/hip_runtime.h>
#include <hip/hip_bf16.h>

#define E_EDGES 1000000
#define N_NODES 100000
#define HDIM 128
#define BM 64
#define LDP 136   // padded LDS row stride for bf16 tiles

typedef __attribute__((ext_vector_type(8))) short short8;
typedef __attribute__((ext_vector_type(4))) float f32x4;

static __device__ __forceinline__ short f2bf(float f) {
  unsigned int u = __float_as_uint(f);
  unsigned int r = (u + 0x7FFFu + ((u >> 16) & 1u)) >> 16;
  return (short)r;
}
static __device__ __forceinline__ float bf2f(short s) {
  return __uint_as_float(((unsigned int)(unsigned short)s) << 16);
}
static __device__ __forceinline__ unsigned int pack_bf16_rn(float lo, float hi) {
  __hip_bfloat162 h = __float22bfloat162_rn(make_float2(lo, hi));
  unsigned int u;
  __builtin_memcpy(&u, &h, 4);
  return u;
}

// ---- k0: transpose + bf16-ize weights: Wt[out][in] row-major ----
__global__ void prep_weights(const float* __restrict__ Wp, const float* __restrict__ Wc,
                             const float* __restrict__ W1, const float* __restrict__ W2,
                             short* __restrict__ wp_t, short* __restrict__ wc_t,
                             short* __restrict__ w1_t, float* __restrict__ w2v) {
  int i = blockIdx.x * 256 + threadIdx.x;
  if (i < HDIM * HDIM) {
    int o = i >> 7, k = i & (HDIM - 1);
    wp_t[i] = f2bf(Wp[k * HDIM + o]);
    wc_t[i] = f2bf(Wc[k * HDIM + o]);
  }
  if (i < HDIM * 3 * HDIM) {
    int o = i / (3 * HDIM), k = i - o * (3 * HDIM);
    w1_t[i] = f2bf(W1[k * HDIM + o]);
  }
  if (i < HDIM) w2v[i] = W2[i];
}

// ---- k1: per-node precompute ----
// x_bf[n] = bf16(x[n]);  A[n] = bf16(lrelu(x@Wp+bp)@W1a + b1);  B[n] = bf16(lrelu(x@Wc+bc)@W1b)
__global__ __launch_bounds__(256) void node_precompute(
    const float* __restrict__ x, const float* __restrict__ b_p,
    const float* __restrict__ b_c, const float* __restrict__ b1,
    const short* __restrict__ wp_t, const short* __restrict__ wc_t,
    const short* __restrict__ w1_t,
    short* __restrict__ x_bf, short* __restrict__ Abuf, short* __restrict__ Bbuf) {
  __shared__ __align__(16) short Xt[BM * LDP];
  __shared__ __align__(16) short Yp[BM * LDP];
  __shared__ __align__(16) short Yc[BM * LDP];

  const int t = threadIdx.x;
  const int n0 = blockIdx.x * BM;

  {
    const int lane16 = t & 15, rq = t >> 4, c0 = lane16 * 8;
#pragma unroll
    for (int pass = 0; pass < 4; ++pass) {
      const int row = pass * 16 + rq;
      const int n = n0 + row;
      short8 v;
      if (n < N_NODES) {
        const float* ps = x + (size_t)n * HDIM + c0;
        float4 a = *(const float4*)ps;
        float4 b = *(const float4*)(ps + 4);
        float f[8] = {a.x, a.y, a.z, a.w, b.x, b.y, b.z, b.w};
#pragma unroll
        for (int j = 0; j < 8; ++j) v[j] = f2bf(f[j]);
        *(short8*)&x_bf[(size_t)n * HDIM + c0] = v;
      } else {
#pragma unroll
        for (int j = 0; j < 8; ++j) v[j] = 0;
      }
      *(short8*)&Xt[row * LDP + c0] = v;
    }
  }
  __syncthreads();

  const int l = t & 63;
  const int w = t >> 6;
  const int lr = l & 15;
  const int lg = l >> 4;
  const int aoff = lr * LDP + lg * 8;
  const int na = w * 32 + lr, nb = na + 16;

  const f32x4 zero4 = {0.f, 0.f, 0.f, 0.f};
  f32x4 ap_[4][2], ac_[4][2];
#pragma unroll
  for (int mi = 0; mi < 4; ++mi) {
    ap_[mi][0] = zero4; ap_[mi][1] = zero4;
    ac_[mi][0] = zero4; ac_[mi][1] = zero4;
  }

  const short* wpA = wp_t + na * HDIM + lg * 8;
  const short* wpB = wp_t + nb * HDIM + lg * 8;
  const short* wcA = wc_t + na * HDIM + lg * 8;
  const short* wcB = wc_t + nb * HDIM + lg * 8;

#pragma unroll
  for (int kk = 0; kk < 4; ++kk) {
    short8 b10 = *(const short8*)(wpA + kk * 32);
    short8 b11 = *(const short8*)(wpB + kk * 32);
    short8 b20 = *(const short8*)(wcA + kk * 32);
    short8 b21 = *(const short8*)(wcB + kk * 32);
#pragma unroll
    for (int mi = 0; mi < 4; ++mi) {
      short8 a8 = *(const short8*)&Xt[mi * 16 * LDP + aoff + kk * 32];
      ap_[mi][0] = __builtin_amdgcn_mfma_f32_16x16x32_bf16(a8, b10, ap_[mi][0], 0, 0, 0);
      ap_[mi][1] = __builtin_amdgcn_mfma_f32_16x16x32_bf16(a8, b11, ap_[mi][1], 0, 0, 0);
      ac_[mi][0] = __builtin_amdgcn_mfma_f32_16x16x32_bf16(a8, b20, ac_[mi][0], 0, 0, 0);
      ac_[mi][1] = __builtin_amdgcn_mfma_f32_16x16x32_bf16(a8, b21, ac_[mi][1], 0, 0, 0);
    }
  }

  {
    const float bpa = b_p[na], bpb = b_p[nb];
    const float bca = b_c[na], bcb = b_c[nb];
#pragma unroll
    for (int mi = 0; mi < 4; ++mi) {
#pragma unroll
      for (int r = 0; r < 4; ++r) {
        const int m = mi * 16 + lg * 4 + r;
        float v0 = ap_[mi][0][r] + bpa; v0 = v0 > 0.f ? v0 : 0.01f * v0;
        float v1 = ap_[mi][1][r] + bpb; v1 = v1 > 0.f ? v1 : 0.01f * v1;
        float u0 = ac_[mi][0][r] + bca; u0 = u0 > 0.f ? u0 : 0.01f * u0;
        float u1 = ac_[mi][1][r] + bcb; u1 = u1 > 0.f ? u1 : 0.01f * u1;
        Yp[m * LDP + na] = f2bf(v0);
        Yp[m * LDP + nb] = f2bf(v1);
        Yc[m * LDP + na] = f2bf(u0);
        Yc[m * LDP + nb] = f2bf(u1);
      }
    }
  }
  __syncthreads();

  f32x4 aa_[4][2], ab_[4][2];
#pragma unroll
  for (int mi = 0; mi < 4; ++mi) {
    aa_[mi][0] = zero4; aa_[mi][1] = zero4;
    ab_[mi][0] = zero4; ab_[mi][1] = zero4;
  }
  const short* w1Aa = w1_t + na * (3 * HDIM) + lg * 8;
  const short* w1Ab = w1_t + nb * (3 * HDIM) + lg * 8;
#pragma unroll
  for (int kk = 0; kk < 4; ++kk) {
    short8 ba0 = *(const short8*)(w1Aa + kk * 32);
    short8 ba1 = *(const short8*)(w1Ab + kk * 32);
    short8 bb0 = *(const short8*)(w1Aa + HDIM + kk * 32);
    short8 bb1 = *(const short8*)(w1Ab + HDIM + kk * 32);
#pragma unroll
    for (int mi = 0; mi < 4; ++mi) {
      short8 ayp = *(const short8*)&Yp[mi * 16 * LDP + aoff + kk * 32];
      short8 ayc = *(const short8*)&Yc[mi * 16 * LDP + aoff + kk * 32];
      aa_[mi][0] = __builtin_amdgcn_mfma_f32_16x16x32_bf16(ayp, ba0, aa_[mi][0], 0, 0, 0);
      aa_[mi][1] = __builtin_amdgcn_mfma_f32_16x16x32_bf16(ayp, ba1, aa_[mi][1], 0, 0, 0);
      ab_[mi][0] = __builtin_amdgcn_mfma_f32_16x16x32_bf16(ayc, bb0, ab_[mi][0], 0, 0, 0);
      ab_[mi][1] = __builtin_amdgcn_mfma_f32_16x16x32_bf16(ayc, bb1, ab_[mi][1], 0, 0, 0);
    }
  }

  {
    const float b1a = b1[na], b1b = b1[nb];
#pragma unroll
    for (int mi = 0; mi < 4; ++mi) {
#pragma unroll
      for (int r = 0; r < 4; ++r) {
        const int m = mi * 16 + lg * 4 + r;
        const int n = n0 + m;
        if (n < N_NODES) {
          Abuf[(size_t)n * HDIM + na] = f2bf(aa_[mi][0][r] + b1a);
          Abuf[(size_t)n * HDIM + nb] = f2bf(aa_[mi][1][r] + b1b);
          Bbuf[(size_t)n * HDIM + na] = f2bf(ab_[mi][0][r]);
          Bbuf[(size_t)n * HDIM + nb] = f2bf(ab_[mi][1][r]);
        }
      }
    }
  }
}

// ---- k2: per-edge: h = relu(S + |x_s-x_d|@W1c); out = sigmoid(h.w2 + b2) ----
// Swapped-operand MFMA: acc = h^T so each lane owns one edge's cols -> cheap epilogue.
__global__ __launch_bounds__(512, 8) void edge_kernel(
    const int* __restrict__ ei, const short* __restrict__ x_bf,
    const short* __restrict__ Abuf, const short* __restrict__ Bbuf,
    const short* __restrict__ w1_t, const float* __restrict__ w2v,
    const float* __restrict__ b2, float* __restrict__ out) {
  __shared__ __align__(16) short Dt[BM * LDP];   // 17408 B
  __shared__ __align__(16) short St[BM * LDP];   // 17408 B
  __shared__ float partial[8][BM];               // 2048 B

  const int t = threadIdx.x;
  const int e0 = blockIdx.x * BM;

  {
    const int lane16 = t & 15, rq = t >> 4, c0 = lane16 * 8;
#pragma unroll
    for (int pass = 0; pass < 2; ++pass) {
      const int row = pass * 32 + rq;
      const int s = ei[e0 + row];
      const int d = ei[E_EDGES + e0 + row];
      short8 p8 = *(const short8*)(x_bf + (size_t)s * HDIM + c0);
      short8 c8 = *(const short8*)(x_bf + (size_t)d * HDIM + c0);
      short8 a8 = *(const short8*)(Abuf + (size_t)s * HDIM + c0);
      short8 b8 = *(const short8*)(Bbuf + (size_t)d * HDIM + c0);
      float df[8], sf[8];
#pragma unroll
      for (int j = 0; j < 8; ++j) {
        df[j] = fabsf(bf2f(p8[j]) - bf2f(c8[j]));
        sf[j] = bf2f(a8[j]) + bf2f(b8[j]);
      }
      uint4 vd, vs;
      vd.x = pack_bf16_rn(df[0], df[1]);
      vd.y = pack_bf16_rn(df[2], df[3]);
      vd.z = pack_bf16_rn(df[4], df[5]);
      vd.w = pack_bf16_rn(df[6], df[7]);
      vs.x = pack_bf16_rn(sf[0], sf[1]);
      vs.y = pack_bf16_rn(sf[2], sf[3]);
      vs.z = pack_bf16_rn(sf[4], sf[5]);
      vs.w = pack_bf16_rn(sf[6], sf[7]);
      *(uint4*)&Dt[row * LDP + c0] = vd;
      *(uint4*)&St[row * LDP + c0] = vs;
    }
  }
  __syncthreads();

  const int l = t & 63;
  const int w = t >> 6;   // 0..7 -> cols w*16..w*16+15
  const int lr = l & 15;
  const int lg = l >> 4;
  const int aoff = lr * LDP + lg * 8;  // Dt fragment read (B operand: free=edge)

  // acc init = S^T: acc[mi][r] = S[edge = mi*16+lr][col = w*16+lg*4+r]
  f32x4 acc[4];
  const int scol = w * 16 + lg * 4;
#pragma unroll
  for (int mi = 0; mi < 4; ++mi) {
    uint2 u = *(const uint2*)&St[(mi * 16 + lr) * LDP + scol];
    acc[mi][0] = __uint_as_float(u.x << 16);
    acc[mi][1] = __uint_as_float(u.x & 0xffff0000u);
    acc[mi][2] = __uint_as_float(u.y << 16);
    acc[mi][3] = __uint_as_float(u.y & 0xffff0000u);
  }

  // GEMM (swapped): acc[mi] = h^T block; A-operand = W1c frag, B-operand = D frag
  const int na = w * 16 + lr;  // w1 fragment free index
  const short* w1D = w1_t + na * (3 * HDIM) + 2 * HDIM + lg * 8;
#pragma unroll
  for (int kk = 0; kk < 4; ++kk) {
    short8 b8 = *(const short8*)(w1D + kk * 32);
#pragma unroll
    for (int mi = 0; mi < 4; ++mi) {
      short8 a8 = *(const short8*)&Dt[mi * 16 * LDP + aoff + kk * 32];
      acc[mi] = __builtin_amdgcn_mfma_f32_16x16x32_bf16(b8, a8, acc[mi], 0, 0, 0);
    }
  }

  // epilogue: per-lane 4-col dot, 2-shfl reduce over lg, write per-wave partial
  {
    const float4 w2q = *(const float4*)&w2v[w * 16 + lg * 4];
#pragma unroll
    for (int mi = 0; mi < 4; ++mi) {
      float p = fmaxf(acc[mi][0], 0.f) * w2q.x + fmaxf(acc[mi][1], 0.f) * w2q.y +
                fmaxf(acc[mi][2], 0.f) * w2q.z + fmaxf(acc[mi][3], 0.f) * w2q.w;
      p += __shfl_xor(p, 16);
      p += __shfl_xor(p, 32);
      if (lg == 0) partial[w][mi * 16 + lr] = p;
    }
  }
  __syncthreads();

  if (t < BM) {
    float z = partial[0][t] + partial[1][t] + partial[2][t] + partial[3][t] +
              partial[4][t] + partial[5][t] + partial[6][t] + partial[7][t] + b2[0];
    out[e0 + t] = 1.0f / (1.0f + __expf(-z));
  }
}

// ---- fallback (validated v2 path) if workspace is too small ----
__global__ __launch_bounds__(512, 4) void edge_weight_fallback(
    const float* __restrict__ x, const int* __restrict__ ei,
    const float* __restrict__ b_p, const float* __restrict__ b_c,
    const float* __restrict__ b1, const float* __restrict__ b2,
    const short* __restrict__ wp_t, const short* __restrict__ wc_t,
    const short* __restrict__ w1_t, const float* __restrict__ w2v,
    float* __restrict__ out) {
  __shared__ __align__(16) short Pt[BM * LDP];
  __shared__ __align__(16) short Ct[BM * LDP];
  __shared__ __align__(16) short Dt[BM * LDP];
  __shared__ float partial[8][BM];

  const int t = threadIdx.x;
  const int e0 = blockIdx.x * BM;
  {
    const int lane16 = t & 15, rq = t >> 4, c0 = lane16 * 8;
#pragma unroll
    for (int pass = 0; pass < 2; ++pass) {
      const int row = pass * 32 + rq;
      const int ip = ei[e0 + row];
      const int ic = ei[E_EDGES + e0 + row];
      const float* ps = x + (size_t)ip * HDIM + c0;
      const float* cs = x + (size_t)ic * HDIM + c0;
      float4 pa = *(const float4*)ps, pb = *(const float4*)(ps + 4);
      float4 ca = *(const float4*)cs, cb = *(const float4*)(cs + 4);
      float pf[8] = {pa.x, pa.y, pa.z, pa.w, pb.x, pb.y, pb.z, pb.w};
      float cf[8] = {ca.x, ca.y, ca.z, ca.w, cb.x, cb.y, cb.z, cb.w};
      short8 vp, vc, vd;
#pragma unroll
      for (int j = 0; j < 8; ++j) {
        vp[j] = f2bf(pf[j]); vc[j] = f2bf(cf[j]); vd[j] = f2bf(fabsf(pf[j] - cf[j]));
      }
      *(short8*)&Pt[row * LDP + c0] = vp;
      *(short8*)&Ct[row * LDP + c0] = vc;
      *(short8*)&Dt[row * LDP + c0] = vd;
    }
  }
  __syncthreads();
  const int l = t & 63, w = t >> 6, lr = l & 15, lg = l >> 4;
  const int n0 = w * 16, na = n0 + lr, aoff = lr * LDP + lg * 8;
  const f32x4 zero4 = {0.f, 0.f, 0.f, 0.f};
  f32x4 acc1[4], acc2[4], acc3[4];
#pragma unroll
  for (int mi = 0; mi < 4; ++mi) { acc1[mi] = zero4; acc2[mi] = zero4; acc3[mi] = zero4; }
  const short* wpA = wp_t + na * HDIM + lg * 8;
  const short* wcA = wc_t + na * HDIM + lg * 8;
  const short* w1A = w1_t + na * (3 * HDIM) + lg * 8;
#pragma unroll
  for (int kk = 0; kk < 4; ++kk) {
    short8 bp8 = *(const short8*)(wpA + kk * 32);
    short8 bc8 = *(const short8*)(wcA + kk * 32);
    short8 bd8 = *(const short8*)(w1A + 2 * HDIM + kk * 32);
#pragma unroll
    for (int mi = 0; mi < 4; ++mi) {
      short8 ap = *(const short8*)&Pt[mi * 16 * LDP + aoff + kk * 32];
      short8 ac = *(const short8*)&Ct[mi * 16 * LDP + aoff + kk * 32];
      short8 ad = *(const short8*)&Dt[mi * 16 * LDP + aoff + kk * 32];
      acc1[mi] = __builtin_amdgcn_mfma_f32_16x16x32_bf16(ap, bp8, acc1[mi], 0, 0, 0);
      acc2[mi] = __builtin_amdgcn_mfma_f32_16x16x32_bf16(ac, bc8, acc2[mi], 0, 0, 0);
      acc3[mi] = __builtin_amdgcn_mfma_f32_16x16x32_bf16(ad, bd8, acc3[mi], 0, 0, 0);
    }
  }
  __syncthreads();
  {
    const float bpa = b_p[na], bca = b_c[na];
#pragma unroll
    for (int mi = 0; mi < 4; ++mi) {
#pragma unroll
      for (int r = 0; r < 4; ++r) {
        const int m = mi * 16 + lg * 4 + r;
        float v0 = acc1[mi][r] + bpa; v0 = v0 > 0.f ? v0 : 0.01f * v0;
        float u0 = acc2[mi][r] + bca; u0 = u0 > 0.f ? u0 : 0.01f * u0;
        Pt[m * LDP + na] = f2bf(v0);
        Ct[m * LDP + na] = f2bf(u0);
      }
    }
  }
  __syncthreads();
#pragma unroll
  for (int kk = 0; kk < 4; ++kk) {
    short8 b0 = *(const short8*)(w1A + kk * 32);
    short8 b1f = *(const short8*)(w1A + HDIM + kk * 32);
#pragma unroll
    for (int mi = 0; mi < 4; ++mi) {
      short8 a0 = *(const short8*)&Pt[mi * 16 * LDP + aoff + kk * 32];
      short8 a1 = *(const short8*)&Ct[mi * 16 * LDP + aoff + kk * 32];
      acc3[mi] = __builtin_amdgcn_mfma_f32_16x16x32_bf16(a0, b0, acc3[mi], 0, 0, 0);
      acc3[mi] = __builtin_amdgcn_mfma_f32_16x16x32_bf16(a1, b1f, acc3[mi], 0, 0, 0);
    }
  }
  {
    const float b1a = b1[na], w2a = w2v[na];
#pragma unroll
    for (int mi = 0; mi < 4; ++mi) {
#pragma unroll
      for (int r = 0; r < 4; ++r) {
        float h0 = acc3[mi][r] + b1a; h0 = h0 > 0.f ? h0 : 0.f;
        float v = h0 * w2a;
        v += __shfl_xor(v, 1); v += __shfl_xor(v, 2);
        v += __shfl_xor(v, 4); v += __shfl_xor(v, 8);
        if (lr == 0) partial[w][mi * 16 + lg * 4 + r] = v;
      }
    }
  }
  __syncthreads();
  if (t < BM) {
    float z = partial[0][t] + partial[1][t] + partial[2][t] + partial[3][t] +
              partial[4][t] + partial[5][t] + partial[6][t] + partial[7][t] + b2[0];
    out[e0 + t] = 1.0f / (1.0f + __expf(-z));
  }
}

extern "C" void kernel_launch(void* const* d_in, const int* in_sizes, int n_in,
                              void* d_out, int out_size, void* d_ws, size_t ws_size,
                              hipStream_t stream) {
  const float* x  = (const float*)d_in[0];
  const int*   ei = (const int*)d_in[1];
  const float* Wp = (const float*)d_in[2];
  const float* bp = (const float*)d_in[3];
  const float* Wc = (const float*)d_in[4];
  const float* bc = (const float*)d_in[5];
  const float* W1 = (const float*)d_in[6];
  const float* b1 = (const float*)d_in[7];
  const float* W2 = (const float*)d_in[8];
  const float* b2 = (const float*)d_in[9];
  float* out = (float*)d_out;

  short* wp_t = (short*)d_ws;
  short* wc_t = wp_t + HDIM * HDIM;
  short* w1_t = wc_t + HDIM * HDIM;
  float* w2v  = (float*)(w1_t + HDIM * 3 * HDIM);
  short* x_bf = (short*)(w2v + HDIM);
  short* Abuf = x_bf + (size_t)N_NODES * HDIM;
  short* Bbuf = Abuf + (size_t)N_NODES * HDIM;

  const size_t needed = (size_t)((char*)(Bbuf + (size_t)N_NODES * HDIM) - (char*)d_ws);
  const int nblocks = E_EDGES / BM;

  prep_weights<<<(HDIM * 3 * HDIM + 255) / 256, 256, 0, stream>>>(Wp, Wc, W1, W2,
                                                                  wp_t, wc_t, w1_t, w2v);
  if (ws_size >= needed) {
    node_precompute<<<(N_NODES + BM - 1) / BM, 256, 0, stream>>>(
        x, bp, bc, b1, wp_t, wc_t, w1_t, x_bf, Abuf, Bbuf);
    edge_kernel<<<nblocks, 512, 0, stream>>>(ei, x_bf, Abuf, Bbuf, w1_t, w2v, b2, out);
  } else {
    edge_weight_fallback<<<nblocks, 512, 0, stream>>>(x, ei, bp, bc, b1, b2,
                                                      wp_t, wc_t, w1_t, w2v, out);
  }
}

// Round 9
// 198.183 us; speedup vs baseline: 2.3898x; 1.0080x over previous
//
#include <hip/hip_runtime.h>
#include <hip/hip_bf16.h>

#define E_EDGES 1000000
#define N_NODES 100000
#define HDIM 128
#define BM 64
#define LDP 136   // padded LDS row stride for bf16 tiles
#define REC 384   // shorts per node record: [x_bf(128) | A(128) | B(128)]

typedef __attribute__((ext_vector_type(8))) short short8;
typedef __attribute__((ext_vector_type(4))) float f32x4;

static __device__ __forceinline__ short f2bf(float f) {
  unsigned int u = __float_as_uint(f);
  unsigned int r = (u + 0x7FFFu + ((u >> 16) & 1u)) >> 16;
  return (short)r;
}
static __device__ __forceinline__ float bf2f(short s) {
  return __uint_as_float(((unsigned int)(unsigned short)s) << 16);
}
// packed |a-b| on 2 bf16 lanes (exact-sub + RNE == f32 path on bf16 inputs)
static __device__ __forceinline__ unsigned int bfsub_abs2(unsigned int a, unsigned int b) {
  __hip_bfloat162 x, y;
  __builtin_memcpy(&x, &a, 4);
  __builtin_memcpy(&y, &b, 4);
  __hip_bfloat162 r = __habs2(__hsub2(x, y));
  unsigned int u;
  __builtin_memcpy(&u, &r, 4);
  return u;
}
static __device__ __forceinline__ unsigned int bfadd2(unsigned int a, unsigned int b) {
  __hip_bfloat162 x, y;
  __builtin_memcpy(&x, &a, 4);
  __builtin_memcpy(&y, &b, 4);
  __hip_bfloat162 r = __hadd2(x, y);
  unsigned int u;
  __builtin_memcpy(&u, &r, 4);
  return u;
}

// ---- k0: transpose + bf16-ize weights: Wt[out][in] row-major ----
__global__ void prep_weights(const float* __restrict__ Wp, const float* __restrict__ Wc,
                             const float* __restrict__ W1, const float* __restrict__ W2,
                             short* __restrict__ wp_t, short* __restrict__ wc_t,
                             short* __restrict__ w1_t, float* __restrict__ w2v) {
  int i = blockIdx.x * 256 + threadIdx.x;
  if (i < HDIM * HDIM) {
    int o = i >> 7, k = i & (HDIM - 1);
    wp_t[i] = f2bf(Wp[k * HDIM + o]);
    wc_t[i] = f2bf(Wc[k * HDIM + o]);
  }
  if (i < HDIM * 3 * HDIM) {
    int o = i / (3 * HDIM), k = i - o * (3 * HDIM);
    w1_t[i] = f2bf(W1[k * HDIM + o]);
  }
  if (i < HDIM) w2v[i] = W2[i];
}

// ---- k1: per-node precompute into interleaved records ----
// rec[n] = [bf16(x[n]) | A(n)=bf16(lrelu(x@Wp+bp)@W1a+b1) | B(n)=bf16(lrelu(x@Wc+bc)@W1b)]
__global__ __launch_bounds__(256) void node_precompute(
    const float* __restrict__ x, const float* __restrict__ b_p,
    const float* __restrict__ b_c, const float* __restrict__ b1,
    const short* __restrict__ wp_t, const short* __restrict__ wc_t,
    const short* __restrict__ w1_t, short* __restrict__ rec) {
  __shared__ __align__(16) short Xt[BM * LDP];
  __shared__ __align__(16) short Yp[BM * LDP];
  __shared__ __align__(16) short Yc[BM * LDP];

  const int t = threadIdx.x;
  const int n0 = blockIdx.x * BM;

  {
    const int lane16 = t & 15, rq = t >> 4, c0 = lane16 * 8;
#pragma unroll
    for (int pass = 0; pass < 4; ++pass) {
      const int row = pass * 16 + rq;
      const int n = n0 + row;
      short8 v;
      if (n < N_NODES) {
        const float* ps = x + (size_t)n * HDIM + c0;
        float4 a = *(const float4*)ps;
        float4 b = *(const float4*)(ps + 4);
        float f[8] = {a.x, a.y, a.z, a.w, b.x, b.y, b.z, b.w};
#pragma unroll
        for (int j = 0; j < 8; ++j) v[j] = f2bf(f[j]);
        *(short8*)&rec[(size_t)n * REC + c0] = v;
      } else {
#pragma unroll
        for (int j = 0; j < 8; ++j) v[j] = 0;
      }
      *(short8*)&Xt[row * LDP + c0] = v;
    }
  }
  __syncthreads();

  const int l = t & 63;
  const int w = t >> 6;
  const int lr = l & 15;
  const int lg = l >> 4;
  const int aoff = lr * LDP + lg * 8;
  const int na = w * 32 + lr, nb = na + 16;

  const f32x4 zero4 = {0.f, 0.f, 0.f, 0.f};
  f32x4 ap_[4][2], ac_[4][2];
#pragma unroll
  for (int mi = 0; mi < 4; ++mi) {
    ap_[mi][0] = zero4; ap_[mi][1] = zero4;
    ac_[mi][0] = zero4; ac_[mi][1] = zero4;
  }

  const short* wpA = wp_t + na * HDIM + lg * 8;
  const short* wpB = wp_t + nb * HDIM + lg * 8;
  const short* wcA = wc_t + na * HDIM + lg * 8;
  const short* wcB = wc_t + nb * HDIM + lg * 8;

#pragma unroll
  for (int kk = 0; kk < 4; ++kk) {
    short8 b10 = *(const short8*)(wpA + kk * 32);
    short8 b11 = *(const short8*)(wpB + kk * 32);
    short8 b20 = *(const short8*)(wcA + kk * 32);
    short8 b21 = *(const short8*)(wcB + kk * 32);
#pragma unroll
    for (int mi = 0; mi < 4; ++mi) {
      short8 a8 = *(const short8*)&Xt[mi * 16 * LDP + aoff + kk * 32];
      ap_[mi][0] = __builtin_amdgcn_mfma_f32_16x16x32_bf16(a8, b10, ap_[mi][0], 0, 0, 0);
      ap_[mi][1] = __builtin_amdgcn_mfma_f32_16x16x32_bf16(a8, b11, ap_[mi][1], 0, 0, 0);
      ac_[mi][0] = __builtin_amdgcn_mfma_f32_16x16x32_bf16(a8, b20, ac_[mi][0], 0, 0, 0);
      ac_[mi][1] = __builtin_amdgcn_mfma_f32_16x16x32_bf16(a8, b21, ac_[mi][1], 0, 0, 0);
    }
  }

  {
    const float bpa = b_p[na], bpb = b_p[nb];
    const float bca = b_c[na], bcb = b_c[nb];
#pragma unroll
    for (int mi = 0; mi < 4; ++mi) {
#pragma unroll
      for (int r = 0; r < 4; ++r) {
        const int m = mi * 16 + lg * 4 + r;
        float v0 = ap_[mi][0][r] + bpa; v0 = v0 > 0.f ? v0 : 0.01f * v0;
        float v1 = ap_[mi][1][r] + bpb; v1 = v1 > 0.f ? v1 : 0.01f * v1;
        float u0 = ac_[mi][0][r] + bca; u0 = u0 > 0.f ? u0 : 0.01f * u0;
        float u1 = ac_[mi][1][r] + bcb; u1 = u1 > 0.f ? u1 : 0.01f * u1;
        Yp[m * LDP + na] = f2bf(v0);
        Yp[m * LDP + nb] = f2bf(v1);
        Yc[m * LDP + na] = f2bf(u0);
        Yc[m * LDP + nb] = f2bf(u1);
      }
    }
  }
  __syncthreads();

  f32x4 aa_[4][2], ab_[4][2];
#pragma unroll
  for (int mi = 0; mi < 4; ++mi) {
    aa_[mi][0] = zero4; aa_[mi][1] = zero4;
    ab_[mi][0] = zero4; ab_[mi][1] = zero4;
  }
  const short* w1Aa = w1_t + na * (3 * HDIM) + lg * 8;
  const short* w1Ab = w1_t + nb * (3 * HDIM) + lg * 8;
#pragma unroll
  for (int kk = 0; kk < 4; ++kk) {
    short8 ba0 = *(const short8*)(w1Aa + kk * 32);
    short8 ba1 = *(const short8*)(w1Ab + kk * 32);
    short8 bb0 = *(const short8*)(w1Aa + HDIM + kk * 32);
    short8 bb1 = *(const short8*)(w1Ab + HDIM + kk * 32);
#pragma unroll
    for (int mi = 0; mi < 4; ++mi) {
      short8 ayp = *(const short8*)&Yp[mi * 16 * LDP + aoff + kk * 32];
      short8 ayc = *(const short8*)&Yc[mi * 16 * LDP + aoff + kk * 32];
      aa_[mi][0] = __builtin_amdgcn_mfma_f32_16x16x32_bf16(ayp, ba0, aa_[mi][0], 0, 0, 0);
      aa_[mi][1] = __builtin_amdgcn_mfma_f32_16x16x32_bf16(ayp, ba1, aa_[mi][1], 0, 0, 0);
      ab_[mi][0] = __builtin_amdgcn_mfma_f32_16x16x32_bf16(ayc, bb0, ab_[mi][0], 0, 0, 0);
      ab_[mi][1] = __builtin_amdgcn_mfma_f32_16x16x32_bf16(ayc, bb1, ab_[mi][1], 0, 0, 0);
    }
  }

  {
    const float b1a = b1[na], b1b = b1[nb];
#pragma unroll
    for (int mi = 0; mi < 4; ++mi) {
#pragma unroll
      for (int r = 0; r < 4; ++r) {
        const int m = mi * 16 + lg * 4 + r;
        const int n = n0 + m;
        if (n < N_NODES) {
          short* rn = rec + (size_t)n * REC;
          rn[HDIM + na] = f2bf(aa_[mi][0][r] + b1a);
          rn[HDIM + nb] = f2bf(aa_[mi][1][r] + b1b);
          rn[2 * HDIM + na] = f2bf(ab_[mi][0][r]);
          rn[2 * HDIM + nb] = f2bf(ab_[mi][1][r]);
        }
      }
    }
  }
}

// ---- k2: per-edge: h = relu(S + |x_s-x_d|@W1c); out = sigmoid(h.w2 + b2) ----
// Swapped-operand MFMA (acc = h^T); packed-bf16 staging; interleaved gathers.
__global__ __launch_bounds__(512, 8) void edge_kernel(
    const int* __restrict__ ei, const short* __restrict__ rec,
    const short* __restrict__ w1_t, const float* __restrict__ w2v,
    const float* __restrict__ b2, float* __restrict__ out) {
  __shared__ __align__(16) short Dt[BM * LDP];   // 17408 B
  __shared__ __align__(16) short St[BM * LDP];   // 17408 B
  __shared__ float partial[8][BM];               // 2048 B

  const int t = threadIdx.x;
  const int e0 = blockIdx.x * BM;

  {
    const int lane16 = t & 15, rq = t >> 4, c0 = lane16 * 8;
#pragma unroll
    for (int pass = 0; pass < 2; ++pass) {
      const int row = pass * 32 + rq;
      const int s = ei[e0 + row];
      const int d = ei[E_EDGES + e0 + row];
      const short* rs = rec + (size_t)s * REC + c0;
      const short* rd = rec + (size_t)d * REC + c0;
      uint4 p = *(const uint4*)rs;                 // x_bf[s]
      uint4 a = *(const uint4*)(rs + HDIM);        // A[s]   (+256B imm)
      uint4 c = *(const uint4*)rd;                 // x_bf[d]
      uint4 b = *(const uint4*)(rd + 2 * HDIM);    // B[d]   (+512B imm)
      uint4 vd, vs;
      vd.x = bfsub_abs2(p.x, c.x);
      vd.y = bfsub_abs2(p.y, c.y);
      vd.z = bfsub_abs2(p.z, c.z);
      vd.w = bfsub_abs2(p.w, c.w);
      vs.x = bfadd2(a.x, b.x);
      vs.y = bfadd2(a.y, b.y);
      vs.z = bfadd2(a.z, b.z);
      vs.w = bfadd2(a.w, b.w);
      *(uint4*)&Dt[row * LDP + c0] = vd;
      *(uint4*)&St[row * LDP + c0] = vs;
    }
  }
  __syncthreads();

  const int l = t & 63;
  const int w = t >> 6;   // 0..7 -> cols w*16..w*16+15
  const int lr = l & 15;
  const int lg = l >> 4;
  const int aoff = lr * LDP + lg * 8;  // Dt fragment read (B operand: free=edge)

  // acc init = S^T: acc[mi][r] = S[edge = mi*16+lr][col = w*16+lg*4+r]
  f32x4 acc[4];
  const int scol = w * 16 + lg * 4;
#pragma unroll
  for (int mi = 0; mi < 4; ++mi) {
    uint2 u = *(const uint2*)&St[(mi * 16 + lr) * LDP + scol];
    acc[mi][0] = __uint_as_float(u.x << 16);
    acc[mi][1] = __uint_as_float(u.x & 0xffff0000u);
    acc[mi][2] = __uint_as_float(u.y << 16);
    acc[mi][3] = __uint_as_float(u.y & 0xffff0000u);
  }

  // GEMM (swapped): A-operand = W1c frag, B-operand = D frag
  const int na = w * 16 + lr;
  const short* w1D = w1_t + na * (3 * HDIM) + 2 * HDIM + lg * 8;
#pragma unroll
  for (int kk = 0; kk < 4; ++kk) {
    short8 b8 = *(const short8*)(w1D + kk * 32);
#pragma unroll
    for (int mi = 0; mi < 4; ++mi) {
      short8 a8 = *(const short8*)&Dt[mi * 16 * LDP + aoff + kk * 32];
      acc[mi] = __builtin_amdgcn_mfma_f32_16x16x32_bf16(b8, a8, acc[mi], 0, 0, 0);
    }
  }

  // epilogue: per-lane 4-col dot, 2-shfl reduce, per-wave partial
  {
    const float4 w2q = *(const float4*)&w2v[w * 16 + lg * 4];
#pragma unroll
    for (int mi = 0; mi < 4; ++mi) {
      float p = fmaxf(acc[mi][0], 0.f) * w2q.x + fmaxf(acc[mi][1], 0.f) * w2q.y +
                fmaxf(acc[mi][2], 0.f) * w2q.z + fmaxf(acc[mi][3], 0.f) * w2q.w;
      p += __shfl_xor(p, 16);
      p += __shfl_xor(p, 32);
      if (lg == 0) partial[w][mi * 16 + lr] = p;
    }
  }
  __syncthreads();

  if (t < BM) {
    float z = partial[0][t] + partial[1][t] + partial[2][t] + partial[3][t] +
              partial[4][t] + partial[5][t] + partial[6][t] + partial[7][t] + b2[0];
    out[e0 + t] = 1.0f / (1.0f + __expf(-z));
  }
}

// ---- fallback (validated v2 path) if workspace is too small ----
__global__ __launch_bounds__(512, 4) void edge_weight_fallback(
    const float* __restrict__ x, const int* __restrict__ ei,
    const float* __restrict__ b_p, const float* __restrict__ b_c,
    const float* __restrict__ b1, const float* __restrict__ b2,
    const short* __restrict__ wp_t, const short* __restrict__ wc_t,
    const short* __restrict__ w1_t, const float* __restrict__ w2v,
    float* __restrict__ out) {
  __shared__ __align__(16) short Pt[BM * LDP];
  __shared__ __align__(16) short Ct[BM * LDP];
  __shared__ __align__(16) short Dt[BM * LDP];
  __shared__ float partial[8][BM];

  const int t = threadIdx.x;
  const int e0 = blockIdx.x * BM;
  {
    const int lane16 = t & 15, rq = t >> 4, c0 = lane16 * 8;
#pragma unroll
    for (int pass = 0; pass < 2; ++pass) {
      const int row = pass * 32 + rq;
      const int ip = ei[e0 + row];
      const int ic = ei[E_EDGES + e0 + row];
      const float* ps = x + (size_t)ip * HDIM + c0;
      const float* cs = x + (size_t)ic * HDIM + c0;
      float4 pa = *(const float4*)ps, pb = *(const float4*)(ps + 4);
      float4 ca = *(const float4*)cs, cb = *(const float4*)(cs + 4);
      float pf[8] = {pa.x, pa.y, pa.z, pa.w, pb.x, pb.y, pb.z, pb.w};
      float cf[8] = {ca.x, ca.y, ca.z, ca.w, cb.x, cb.y, cb.z, cb.w};
      short8 vp, vc, vd;
#pragma unroll
      for (int j = 0; j < 8; ++j) {
        vp[j] = f2bf(pf[j]); vc[j] = f2bf(cf[j]); vd[j] = f2bf(fabsf(pf[j] - cf[j]));
      }
      *(short8*)&Pt[row * LDP + c0] = vp;
      *(short8*)&Ct[row * LDP + c0] = vc;
      *(short8*)&Dt[row * LDP + c0] = vd;
    }
  }
  __syncthreads();
  const int l = t & 63, w = t >> 6, lr = l & 15, lg = l >> 4;
  const int n0 = w * 16, na = n0 + lr, aoff = lr * LDP + lg * 8;
  const f32x4 zero4 = {0.f, 0.f, 0.f, 0.f};
  f32x4 acc1[4], acc2[4], acc3[4];
#pragma unroll
  for (int mi = 0; mi < 4; ++mi) { acc1[mi] = zero4; acc2[mi] = zero4; acc3[mi] = zero4; }
  const short* wpA = wp_t + na * HDIM + lg * 8;
  const short* wcA = wc_t + na * HDIM + lg * 8;
  const short* w1A = w1_t + na * (3 * HDIM) + lg * 8;
#pragma unroll
  for (int kk = 0; kk < 4; ++kk) {
    short8 bp8 = *(const short8*)(wpA + kk * 32);
    short8 bc8 = *(const short8*)(wcA + kk * 32);
    short8 bd8 = *(const short8*)(w1A + 2 * HDIM + kk * 32);
#pragma unroll
    for (int mi = 0; mi < 4; ++mi) {
      short8 ap = *(const short8*)&Pt[mi * 16 * LDP + aoff + kk * 32];
      short8 ac = *(const short8*)&Ct[mi * 16 * LDP + aoff + kk * 32];
      short8 ad = *(const short8*)&Dt[mi * 16 * LDP + aoff + kk * 32];
      acc1[mi] = __builtin_amdgcn_mfma_f32_16x16x32_bf16(ap, bp8, acc1[mi], 0, 0, 0);
      acc2[mi] = __builtin_amdgcn_mfma_f32_16x16x32_bf16(ac, bc8, acc2[mi], 0, 0, 0);
      acc3[mi] = __builtin_amdgcn_mfma_f32_16x16x32_bf16(ad, bd8, acc3[mi], 0, 0, 0);
    }
  }
  __syncthreads();
  {
    const float bpa = b_p[na], bca = b_c[na];
#pragma unroll
    for (int mi = 0; mi < 4; ++mi) {
#pragma unroll
      for (int r = 0; r < 4; ++r) {
        const int m = mi * 16 + lg * 4 + r;
        float v0 = acc1[mi][r] + bpa; v0 = v0 > 0.f ? v0 : 0.01f * v0;
        float u0 = acc2[mi][r] + bca; u0 = u0 > 0.f ? u0 : 0.01f * u0;
        Pt[m * LDP + na] = f2bf(v0);
        Ct[m * LDP + na] = f2bf(u0);
      }
    }
  }
  __syncthreads();
#pragma unroll
  for (int kk = 0; kk < 4; ++kk) {
    short8 b0 = *(const short8*)(w1A + kk * 32);
    short8 b1f = *(const short8*)(w1A + HDIM + kk * 32);
#pragma unroll
    for (int mi = 0; mi < 4; ++mi) {
      short8 a0 = *(const short8*)&Pt[mi * 16 * LDP + aoff + kk * 32];
      short8 a1 = *(const short8*)&Ct[mi * 16 * LDP + aoff + kk * 32];
      acc3[mi] = __builtin_amdgcn_mfma_f32_16x16x32_bf16(a0, b0, acc3[mi], 0, 0, 0);
      acc3[mi] = __builtin_amdgcn_mfma_f32_16x16x32_bf16(a1, b1f, acc3[mi], 0, 0, 0);
    }
  }
  {
    const float b1a = b1[na], w2a = w2v[na];
#pragma unroll
    for (int mi = 0; mi < 4; ++mi) {
#pragma unroll
      for (int r = 0; r < 4; ++r) {
        float h0 = acc3[mi][r] + b1a; h0 = h0 > 0.f ? h0 : 0.f;
        float v = h0 * w2a;
        v += __shfl_xor(v, 1); v += __shfl_xor(v, 2);
        v += __shfl_xor(v, 4); v += __shfl_xor(v, 8);
        if (lr == 0) partial[w][mi * 16 + lg * 4 + r] = v;
      }
    }
  }
  __syncthreads();
  if (t < BM) {
    float z = partial[0][t] + partial[1][t] + partial[2][t] + partial[3][t] +
              partial[4][t] + partial[5][t] + partial[6][t] + partial[7][t] + b2[0];
    out[e0 + t] = 1.0f / (1.0f + __expf(-z));
  }
}

extern "C" void kernel_launch(void* const* d_in, const int* in_sizes, int n_in,
                              void* d_out, int out_size, void* d_ws, size_t ws_size,
                              hipStream_t stream) {
  const float* x  = (const float*)d_in[0];
  const int*   ei = (const int*)d_in[1];
  const float* Wp = (const float*)d_in[2];
  const float* bp = (const float*)d_in[3];
  const float* Wc = (const float*)d_in[4];
  const float* bc = (const float*)d_in[5];
  const float* W1 = (const float*)d_in[6];
  const float* b1 = (const float*)d_in[7];
  const float* W2 = (const float*)d_in[8];
  const float* b2 = (const float*)d_in[9];
  float* out = (float*)d_out;

  short* wp_t = (short*)d_ws;
  short* wc_t = wp_t + HDIM * HDIM;
  short* w1_t = wc_t + HDIM * HDIM;
  float* w2v  = (float*)(w1_t + HDIM * 3 * HDIM);
  short* rec  = (short*)(w2v + HDIM);

  const size_t needed = (size_t)((char*)(rec + (size_t)N_NODES * REC) - (char*)d_ws);
  const int nblocks = E_EDGES / BM;

  prep_weights<<<(HDIM * 3 * HDIM + 255) / 256, 256, 0, stream>>>(Wp, Wc, W1, W2,
                                                                  wp_t, wc_t, w1_t, w2v);
  if (ws_size >= needed) {
    node_precompute<<<(N_NODES + BM - 1) / BM, 256, 0, stream>>>(
        x, bp, bc, b1, wp_t, wc_t, w1_t, rec);
    edge_kernel<<<nblocks, 512, 0, stream>>>(ei, rec, w1_t, w2v, b2, out);
  } else {
    edge_weight_fallback<<<nblocks, 512, 0, stream>>>(x, ei, bp, bc, b1, b2,
                                                      wp_t, wc_t, w1_t, w2v, out);
  }
}